// Round 1
// baseline (607.599 us; speedup 1.0000x reference)
//
#include <hip/hip_runtime.h>

#define N_NODES 100000
#define D_IN 32
#define D_HID 64
#define D_OUT 32

// ---------------- degree accumulation ----------------
__global__ void deg_kernel(const int* __restrict__ src, const int* __restrict__ dst,
                           float* __restrict__ deg_out, float* __restrict__ deg_in, int E) {
    int stride = gridDim.x * blockDim.x;
    for (int e = blockIdx.x * blockDim.x + threadIdx.x; e < E; e += stride) {
        atomicAdd(&deg_out[src[e]], 1.0f);
        atomicAdd(&deg_in[dst[e]], 1.0f);
    }
}

// in-place deg -> rsqrt(max(deg,1)); n covers both arrays (contiguous)
__global__ void norm_kernel(float* __restrict__ deg, int n) {
    int i = blockIdx.x * blockDim.x + threadIdx.x;
    if (i < n) {
        float d = deg[i];
        deg[i] = rsqrtf(d < 1.0f ? 1.0f : d);
    }
}

// ---------------- layer 1 scatter: agg1[dst] += x[src]*norm_src[src] ----------------
__global__ void scatter1_kernel(const float* __restrict__ x, const int* __restrict__ src,
                                const int* __restrict__ dst, const float* __restrict__ norm_src,
                                float* __restrict__ agg, int total) {
    int t = blockIdx.x * blockDim.x + threadIdx.x;
    if (t >= total) return;
    int e = t >> 5;          // edge index
    int j = t & 31;          // feature index
    int s = src[e];
    int d = dst[e];
    float v = x[(long)s * D_IN + j] * norm_src[s];
    atomicAdd(&agg[(long)d * D_IN + j], v);
}

// ---------------- layer 1 GEMM: z1 = (agg1 * norm_dst) @ W1 + b1 ----------------
__global__ void gemm1_kernel(const float* __restrict__ agg, const float* __restrict__ norm_dst,
                             const float* __restrict__ W1, const float* __restrict__ b1,
                             float* __restrict__ z1, int n_nodes) {
    __shared__ float Ws[D_IN * D_HID];   // 8 KB
    int t = threadIdx.x;
    for (int i = t; i < D_IN * D_HID; i += blockDim.x) Ws[i] = W1[i];
    __syncthreads();
    int nl = t / D_HID;                  // node within block (4 per 256-block)
    int j  = t % D_HID;
    int n  = blockIdx.x * (blockDim.x / D_HID) + nl;
    if (n >= n_nodes) return;
    const float* row = agg + (long)n * D_IN;
    float acc = 0.0f;
#pragma unroll
    for (int k = 0; k < D_IN; ++k) acc += row[k] * Ws[k * D_HID + j];
    z1[(long)n * D_HID + j] = acc * norm_dst[n] + b1[j];
}

// ---------------- layer 2 GEMM (pre-scatter): y = norm_src * (z1 @ W2) ----------------
__global__ void gemm2_kernel(const float* __restrict__ z1, const float* __restrict__ norm_src,
                             const float* __restrict__ W2, float* __restrict__ y, int n_nodes) {
    __shared__ float Ws[D_HID * D_OUT];  // 8 KB
    int t = threadIdx.x;
    for (int i = t; i < D_HID * D_OUT; i += blockDim.x) Ws[i] = W2[i];
    __syncthreads();
    int nl = t / D_OUT;                  // 8 nodes per 256-block
    int j  = t % D_OUT;
    int n  = blockIdx.x * (blockDim.x / D_OUT) + nl;
    if (n >= n_nodes) return;
    const float* row = z1 + (long)n * D_HID;
    float acc = 0.0f;
#pragma unroll
    for (int k = 0; k < D_HID; ++k) acc += row[k] * Ws[k * D_OUT + j];
    y[(long)n * D_OUT + j] = acc * norm_src[n];
}

// ---------------- layer 2 scatter: out[dst] += y[src] ----------------
__global__ void scatter2_kernel(const float* __restrict__ y, const int* __restrict__ src,
                                const int* __restrict__ dst, float* __restrict__ out, int total) {
    int t = blockIdx.x * blockDim.x + threadIdx.x;
    if (t >= total) return;
    int e = t >> 5;
    int j = t & 31;
    int s = src[e];
    int d = dst[e];
    atomicAdd(&out[(long)d * D_OUT + j], y[(long)s * D_OUT + j]);
}

// ---------------- final: out = out * norm_dst + b2 ----------------
__global__ void final_kernel(float* __restrict__ out, const float* __restrict__ norm_dst,
                             const float* __restrict__ b2, int total) {
    int i = blockIdx.x * blockDim.x + threadIdx.x;
    if (i >= total) return;
    int n = i >> 5;   // D_OUT == 32
    int j = i & 31;
    out[i] = out[i] * norm_dst[n] + b2[j];
}

extern "C" void kernel_launch(void* const* d_in, const int* in_sizes, int n_in,
                              void* d_out, int out_size, void* d_ws, size_t ws_size,
                              hipStream_t stream) {
    const float* x   = (const float*)d_in[0];
    const int*   src = (const int*)d_in[1];
    const int*   dst = (const int*)d_in[2];
    const float* W1  = (const float*)d_in[3];
    const float* b1  = (const float*)d_in[4];
    const float* W2  = (const float*)d_in[5];
    const float* b2  = (const float*)d_in[6];
    float* out = (float*)d_out;

    const int N = N_NODES;
    const int E = in_sizes[1];

    // workspace layout (floats)
    float* ws       = (float*)d_ws;
    float* deg_out  = ws;                  // [N]
    float* deg_in   = ws + N;              // [N]
    float* agg1     = ws + 2 * N;          // [N*32]
    float* z1       = ws + 2 * N + N * D_IN;   // [N*64]
    float* y        = agg1;                // reuse agg1 for layer-2 pre-scatter values

    // zero: deg_out, deg_in, agg1 (contiguous prefix) and d_out (used as accumulator)
    hipMemsetAsync(d_ws, 0, (size_t)(2 * N + N * D_IN) * sizeof(float), stream);
    hipMemsetAsync(d_out, 0, (size_t)out_size * sizeof(float), stream);

    // degrees
    deg_kernel<<<2048, 256, 0, stream>>>(src, dst, deg_out, deg_in, E);
    // norms (both arrays in one pass; deg_out->norm_src, deg_in->norm_dst)
    norm_kernel<<<(2 * N + 255) / 256, 256, 0, stream>>>(deg_out, 2 * N);
    const float* norm_src = deg_out;
    const float* norm_dst = deg_in;

    // layer 1
    int total1 = E * D_IN;
    scatter1_kernel<<<(total1 + 255) / 256, 256, 0, stream>>>(x, src, dst, norm_src, agg1, total1);
    gemm1_kernel<<<(N + 3) / 4, 256, 0, stream>>>(agg1, norm_dst, W1, b1, z1, N);

    // layer 2: dense part first (so scatter is 32-wide, not 64-wide)
    gemm2_kernel<<<(N + 7) / 8, 256, 0, stream>>>(z1, norm_src, W2, y, N);
    int total2 = E * D_OUT;
    scatter2_kernel<<<(total2 + 255) / 256, 256, 0, stream>>>(y, src, dst, out, total2);
    final_kernel<<<(out_size + 255) / 256, 256, 0, stream>>>(out, norm_dst, b2, out_size);
}

// Round 2
// 501.545 us; speedup vs baseline: 1.2115x; 1.2115x over previous
//
#include <hip/hip_runtime.h>

#define N_NODES 100000
#define D_IN 32
#define D_HID 64
#define D_OUT 32

// ---------------- degree histograms (int) ----------------
__global__ void hist_kernel(const int* __restrict__ src, const int* __restrict__ dst,
                            int* __restrict__ cnt_src, int* __restrict__ cnt_dst, int E) {
    int stride = gridDim.x * blockDim.x;
    for (int e = blockIdx.x * blockDim.x + threadIdx.x; e < E; e += stride) {
        atomicAdd(&cnt_src[src[e]], 1);
        atomicAdd(&cnt_dst[dst[e]], 1);
    }
}

// norms[i] = rsqrt(max(cnt[i],1)); cnt is the contiguous [cnt_src|cnt_dst] block
__global__ void norm_kernel(const int* __restrict__ cnt, float* __restrict__ norms, int n2) {
    int i = blockIdx.x * blockDim.x + threadIdx.x;
    if (i < n2) {
        int d = cnt[i];
        norms[i] = rsqrtf((float)(d < 1 ? 1 : d));
    }
}

// ---------------- 3-kernel exclusive scan of cnt_dst -> rowptr ----------------
__global__ void scan1_kernel(const int* __restrict__ cnt, int* __restrict__ excl,
                             int* __restrict__ bsums, int n) {
    __shared__ int s[256];
    int tid = threadIdx.x;
    int i = blockIdx.x * 256 + tid;
    int v = (i < n) ? cnt[i] : 0;
    s[tid] = v;
    __syncthreads();
    for (int off = 1; off < 256; off <<= 1) {
        int tv = (tid >= off) ? s[tid - off] : 0;
        __syncthreads();
        s[tid] += tv;
        __syncthreads();
    }
    if (i < n) excl[i] = s[tid] - v;          // exclusive within block
    if (tid == 255) bsums[blockIdx.x] = s[255];
}

__global__ void scan2_kernel(int* __restrict__ bsums, int nb) {
    __shared__ int s[512];
    int tid = threadIdx.x;
    int v = (tid < nb) ? bsums[tid] : 0;
    s[tid] = v;
    __syncthreads();
    for (int off = 1; off < 512; off <<= 1) {
        int tv = (tid >= off) ? s[tid - off] : 0;
        __syncthreads();
        s[tid] += tv;
        __syncthreads();
    }
    if (tid < nb) bsums[tid] = s[tid] - v;     // exclusive block offsets
}

__global__ void scan3_kernel(int* __restrict__ rowptr, int* __restrict__ cursor,
                             const int* __restrict__ bsums, int n, int E) {
    int i = blockIdx.x * 256 + threadIdx.x;
    if (i < n) {
        int v = rowptr[i] + bsums[blockIdx.x];
        rowptr[i] = v;
        cursor[i] = v;
    }
    if (i == 0) rowptr[n] = E;
}

// ---------------- CSR fill: colidx grouped by dst holds src ----------------
__global__ void fill_kernel(const int* __restrict__ src, const int* __restrict__ dst,
                            int* __restrict__ cursor, int* __restrict__ colidx, int E) {
    int e = blockIdx.x * 256 + threadIdx.x;
    if (e < E) {
        int pos = atomicAdd(&cursor[dst[e]], 1);
        colidx[pos] = src[e];
    }
}

// ---------------- layer 1 fused: gather-agg + GEMM1 + GEMM2 -> y ----------------
// y[n] = norm_src[n] * ( ( norm_dst[n] * (sum_{e in in(n)} x[col]*norm_src[col]) @ W1 + b1 ) @ W2 )
__global__ __launch_bounds__(256) void layer1_fused(
    const float* __restrict__ x, const int* __restrict__ colidx,
    const int* __restrict__ rowptr, const float* __restrict__ norm_src,
    const float* __restrict__ norm_dst,
    const float* __restrict__ W1, const float* __restrict__ b1,
    const float* __restrict__ W2, float* __restrict__ y, int n_nodes) {
    __shared__ float W1s[D_IN * D_HID];    // 8 KB
    __shared__ float W2s[D_HID * D_OUT];   // 8 KB
    __shared__ float b1s[D_HID];
    __shared__ float accs[4][D_IN];
    __shared__ float z1s[4][D_HID];
    int t = threadIdx.x;
    for (int i = t; i < D_IN * D_HID; i += 256) W1s[i] = W1[i];
    for (int i = t; i < D_HID * D_OUT; i += 256) W2s[i] = W2[i];
    if (t < D_HID) b1s[t] = b1[t];
    __syncthreads();

    int w = t >> 6, lane = t & 63, j = lane & 31, eh = lane >> 5;
    for (int n = blockIdx.x * 4 + w; n < n_nodes; n += gridDim.x * 4) {
        int start = rowptr[n], end = rowptr[n + 1];
        // gather-aggregate: 2 edges in parallel (half-waves), 32 features each
        float acc = 0.0f;
        for (int e = start + eh; e < end; e += 2) {
            int c = colidx[e];
            acc += x[(long)c * D_IN + j] * norm_src[c];
        }
        acc += __shfl_xor(acc, 32);
        if (lane < 32) accs[w][j] = acc;   // same-wave LDS, no barrier needed
        // GEMM1: z1[o] = norm_dst[n] * sum_k acc[k]*W1[k][o] + b1[o], o = lane
        float nd = norm_dst[n];
        float s1 = 0.0f;
#pragma unroll
        for (int k = 0; k < D_IN; ++k) s1 += accs[w][k] * W1s[k * D_HID + lane];
        z1s[w][lane] = nd * s1 + b1s[lane];
        // GEMM2: y[j] = norm_src[n] * sum_k z1[k]*W2[k][j]; split k over half-waves
        float s2 = 0.0f;
        int kb = eh * 32;
#pragma unroll
        for (int kk = 0; kk < 32; ++kk) s2 += z1s[w][kb + kk] * W2s[(kb + kk) * D_OUT + j];
        s2 += __shfl_xor(s2, 32);
        if (lane < 32) y[(long)n * D_OUT + j] = norm_src[n] * s2;
    }
}

// ---------------- layer 2: gather-agg + scale + bias -> out ----------------
__global__ __launch_bounds__(256) void agg2_kernel(
    const float* __restrict__ y, const int* __restrict__ colidx,
    const int* __restrict__ rowptr, const float* __restrict__ norm_dst,
    const float* __restrict__ b2, float* __restrict__ out, int n_nodes) {
    int t = threadIdx.x;
    int w = t >> 6, lane = t & 63, j = lane & 31, eh = lane >> 5;
    for (int n = blockIdx.x * 4 + w; n < n_nodes; n += gridDim.x * 4) {
        int start = rowptr[n], end = rowptr[n + 1];
        float acc = 0.0f;
        for (int e = start + eh; e < end; e += 2) {
            int c = colidx[e];
            acc += y[(long)c * D_OUT + j];
        }
        acc += __shfl_xor(acc, 32);
        if (lane < 32) out[(long)n * D_OUT + j] = acc * norm_dst[n] + b2[j];
    }
}

extern "C" void kernel_launch(void* const* d_in, const int* in_sizes, int n_in,
                              void* d_out, int out_size, void* d_ws, size_t ws_size,
                              hipStream_t stream) {
    const float* x   = (const float*)d_in[0];
    const int*   src = (const int*)d_in[1];
    const int*   dst = (const int*)d_in[2];
    const float* W1  = (const float*)d_in[3];
    const float* b1  = (const float*)d_in[4];
    const float* W2  = (const float*)d_in[5];
    const float* b2  = (const float*)d_in[6];
    float* out = (float*)d_out;

    const int N = N_NODES;
    const int E = in_sizes[1];

    // workspace layout (ints then floats), total ~21.2 MB
    int* ws_i    = (int*)d_ws;
    int* cnt_src = ws_i;                 // [N]  (reused as cursor after norms)
    int* cnt_dst = ws_i + N;             // [N]
    int* rowptr  = ws_i + 2 * N;         // [N+1]
    int* bsums   = ws_i + 3 * N + 1;     // [512]
    int* colidx  = ws_i + 3 * N + 513;   // [E]
    float* norms = (float*)(colidx + E); // [2N]: norm_src | norm_dst
    float* yv    = norms + 2 * N;        // [32N]

    // zero only the histograms; y and out are fully overwritten
    hipMemsetAsync(ws_i, 0, (size_t)(2 * N) * sizeof(int), stream);

    hist_kernel<<<2048, 256, 0, stream>>>(src, dst, cnt_src, cnt_dst, E);
    norm_kernel<<<(2 * N + 255) / 256, 256, 0, stream>>>(ws_i, norms, 2 * N);

    int nb = (N + 255) / 256;            // 391 <= 512
    scan1_kernel<<<nb, 256, 0, stream>>>(cnt_dst, rowptr, bsums, N);
    scan2_kernel<<<1, 512, 0, stream>>>(bsums, nb);
    scan3_kernel<<<nb, 256, 0, stream>>>(rowptr, cnt_src /*cursor*/, bsums, N, E);
    fill_kernel<<<(E + 255) / 256, 256, 0, stream>>>(src, dst, cnt_src, colidx, E);

    layer1_fused<<<2048, 256, 0, stream>>>(x, colidx, rowptr, norms, norms + N,
                                           W1, b1, W2, yv, N);
    agg2_kernel<<<2048, 256, 0, stream>>>(yv, colidx, rowptr, norms + N, b2, out, N);
}

// Round 4
// 386.016 us; speedup vs baseline: 1.5740x; 1.2993x over previous
//
#include <hip/hip_runtime.h>

#define N_NODES 100000
#define D_IN 32
#define D_HID 64
#define D_OUT 32

// ---------------- degree histograms (int) ----------------
__global__ void hist_kernel(const int* __restrict__ src, const int* __restrict__ dst,
                            int* __restrict__ cnt_src, int* __restrict__ cnt_dst, int E) {
    int stride = gridDim.x * blockDim.x;
    for (int e = blockIdx.x * blockDim.x + threadIdx.x; e < E; e += stride) {
        atomicAdd(&cnt_src[src[e]], 1);
        atomicAdd(&cnt_dst[dst[e]], 1);
    }
}

// norms[i] = rsqrt(max(cnt[i],1)); cnt is the contiguous [cnt_src|cnt_dst] block
__global__ void norm_kernel(const int* __restrict__ cnt, float* __restrict__ norms, int n2) {
    int i = blockIdx.x * blockDim.x + threadIdx.x;
    if (i < n2) {
        int d = cnt[i];
        norms[i] = rsqrtf((float)(d < 1 ? 1 : d));
    }
}

// ---------------- 3-kernel exclusive scan of cnt_dst -> rowptr ----------------
__global__ void scan1_kernel(const int* __restrict__ cnt, int* __restrict__ excl,
                             int* __restrict__ bsums, int n) {
    __shared__ int s[256];
    int tid = threadIdx.x;
    int i = blockIdx.x * 256 + tid;
    int v = (i < n) ? cnt[i] : 0;
    s[tid] = v;
    __syncthreads();
    for (int off = 1; off < 256; off <<= 1) {
        int tv = (tid >= off) ? s[tid - off] : 0;
        __syncthreads();
        s[tid] += tv;
        __syncthreads();
    }
    if (i < n) excl[i] = s[tid] - v;
    if (tid == 255) bsums[blockIdx.x] = s[255];
}

__global__ void scan2_kernel(int* __restrict__ bsums, int nb) {
    __shared__ int s[512];
    int tid = threadIdx.x;
    int v = (tid < nb) ? bsums[tid] : 0;
    s[tid] = v;
    __syncthreads();
    for (int off = 1; off < 512; off <<= 1) {
        int tv = (tid >= off) ? s[tid - off] : 0;
        __syncthreads();
        s[tid] += tv;
        __syncthreads();
    }
    if (tid < nb) bsums[tid] = s[tid] - v;
}

__global__ void scan3_kernel(int* __restrict__ rowptr, int* __restrict__ cursor,
                             const int* __restrict__ bsums, int n, int E) {
    int i = blockIdx.x * 256 + threadIdx.x;
    if (i < n) {
        int v = rowptr[i] + bsums[blockIdx.x];
        rowptr[i] = v;
        cursor[i] = v;
    }
    if (i == 0) rowptr[n] = E;
}

// ---------------- CSR fill: colidx grouped by dst holds src ----------------
__global__ void fill_kernel(const int* __restrict__ src, const int* __restrict__ dst,
                            int* __restrict__ cursor, int* __restrict__ colidx, int E) {
    int e = blockIdx.x * 256 + threadIdx.x;
    if (e < E) {
        int pos = atomicAdd(&cursor[dst[e]], 1);
        colidx[pos] = src[e];
    }
}

// ---------------- layer 1 fused: float4 gather-agg + GEMM1 + GEMM2 -> y ----------------
// lane layout for gather: eh = lane>>3 (edge slot 0..7), q = lane&7 (feature quad)
__global__ __launch_bounds__(256) void layer1_fused(
    const float4* __restrict__ x4, const int* __restrict__ colidx,
    const int* __restrict__ rowptr, const float* __restrict__ norm_src,
    const float* __restrict__ norm_dst,
    const float* __restrict__ W1, const float* __restrict__ b1,
    const float* __restrict__ W2, float* __restrict__ y, int n_nodes) {
    __shared__ float W1s[D_IN * D_HID];    // 8 KB
    __shared__ float W2s[D_HID * D_OUT];   // 8 KB
    __shared__ float b1s[D_HID];
    __shared__ float accs[4][D_IN];
    __shared__ float z1s[4][D_HID];
    int t = threadIdx.x;
    for (int i = t; i < D_IN * D_HID; i += 256) W1s[i] = W1[i];
    for (int i = t; i < D_HID * D_OUT; i += 256) W2s[i] = W2[i];
    if (t < D_HID) b1s[t] = b1[t];
    __syncthreads();

    int w = t >> 6, lane = t & 63;
    int eh = lane >> 3;          // edge slot
    int q  = lane & 7;           // feature quad
    int j  = lane & 31;          // GEMM2 output feature
    int kb = (lane >> 5) * 32;   // GEMM2 k-half base

    for (int n = blockIdx.x * 4 + w; n < n_nodes; n += gridDim.x * 4) {
        int start = rowptr[n], end = rowptr[n + 1];
        int deg = end - start;
        float ax = 0.f, ay = 0.f, az = 0.f, aw = 0.f;
        for (int base = 0; base < deg; base += 64) {
            int rem = deg - base;
            int lim = rem < 64 ? rem : 64;
            int lim_up = (lim + 7) & ~7;   // wave-uniform trip count
            int c_reg = (lane < lim) ? colidx[start + base + lane] : 0;
            for (int i = eh; i < lim_up; i += 8) {
                int c = __shfl(c_reg, i);  // all 64 lanes active here
                if (i < lim) {
                    float ns = norm_src[c];
                    float4 v = x4[(long)c * 8 + q];
                    ax = fmaf(v.x, ns, ax); ay = fmaf(v.y, ns, ay);
                    az = fmaf(v.z, ns, az); aw = fmaf(v.w, ns, aw);
                }
            }
        }
        // reduce across edge slots (lane bits 3,4,5)
        ax += __shfl_xor(ax, 8);  ay += __shfl_xor(ay, 8);  az += __shfl_xor(az, 8);  aw += __shfl_xor(aw, 8);
        ax += __shfl_xor(ax, 16); ay += __shfl_xor(ay, 16); az += __shfl_xor(az, 16); aw += __shfl_xor(aw, 16);
        ax += __shfl_xor(ax, 32); ay += __shfl_xor(ay, 32); az += __shfl_xor(az, 32); aw += __shfl_xor(aw, 32);
        if (lane < 8) {
            accs[w][q * 4 + 0] = ax; accs[w][q * 4 + 1] = ay;
            accs[w][q * 4 + 2] = az; accs[w][q * 4 + 3] = aw;
        }
        // GEMM1: z1[lane] = norm_dst[n]*sum_k accs[k]*W1[k][lane] + b1[lane]
        float nd = norm_dst[n];
        float s1 = 0.f;
#pragma unroll
        for (int k = 0; k < D_IN; ++k) s1 = fmaf(accs[w][k], W1s[k * D_HID + lane], s1);
        z1s[w][lane] = nd * s1 + b1s[lane];
        // GEMM2: y[j] = norm_src[n]*sum_k z1[k]*W2[k][j], k split over half-waves
        float s2 = 0.f;
#pragma unroll
        for (int kk = 0; kk < 32; ++kk) s2 = fmaf(z1s[w][kb + kk], W2s[(kb + kk) * D_OUT + j], s2);
        s2 += __shfl_xor(s2, 32);
        if (lane < 32) y[(long)n * D_OUT + j] = norm_src[n] * s2;
    }
}

// ---------------- layer 2: float4 gather-agg + scale + bias -> out ----------------
__global__ __launch_bounds__(256) void agg2_kernel(
    const float4* __restrict__ y4, const int* __restrict__ colidx,
    const int* __restrict__ rowptr, const float* __restrict__ norm_dst,
    const float* __restrict__ b2, float4* __restrict__ out4, int n_nodes) {
    int t = threadIdx.x;
    int w = t >> 6, lane = t & 63;
    int eh = lane >> 3, q = lane & 7;
    for (int n = blockIdx.x * 4 + w; n < n_nodes; n += gridDim.x * 4) {
        int start = rowptr[n], end = rowptr[n + 1];
        int deg = end - start;
        float ax = 0.f, ay = 0.f, az = 0.f, aw = 0.f;
        for (int base = 0; base < deg; base += 64) {
            int rem = deg - base;
            int lim = rem < 64 ? rem : 64;
            int lim_up = (lim + 7) & ~7;
            int c_reg = (lane < lim) ? colidx[start + base + lane] : 0;
            for (int i = eh; i < lim_up; i += 8) {
                int c = __shfl(c_reg, i);
                if (i < lim) {
                    float4 v = y4[(long)c * 8 + q];
                    ax += v.x; ay += v.y; az += v.z; aw += v.w;
                }
            }
        }
        ax += __shfl_xor(ax, 8);  ay += __shfl_xor(ay, 8);  az += __shfl_xor(az, 8);  aw += __shfl_xor(aw, 8);
        ax += __shfl_xor(ax, 16); ay += __shfl_xor(ay, 16); az += __shfl_xor(az, 16); aw += __shfl_xor(aw, 16);
        ax += __shfl_xor(ax, 32); ay += __shfl_xor(ay, 32); az += __shfl_xor(az, 32); aw += __shfl_xor(aw, 32);
        if (lane < 8) {
            float nd = norm_dst[n];
            const float4 bb = ((const float4*)b2)[q];
            float4 o;
            o.x = fmaf(ax, nd, bb.x); o.y = fmaf(ay, nd, bb.y);
            o.z = fmaf(az, nd, bb.z); o.w = fmaf(aw, nd, bb.w);
            out4[(long)n * 8 + q] = o;
        }
    }
}

extern "C" void kernel_launch(void* const* d_in, const int* in_sizes, int n_in,
                              void* d_out, int out_size, void* d_ws, size_t ws_size,
                              hipStream_t stream) {
    const float* x   = (const float*)d_in[0];
    const int*   src = (const int*)d_in[1];
    const int*   dst = (const int*)d_in[2];
    const float* W1  = (const float*)d_in[3];
    const float* b1  = (const float*)d_in[4];
    const float* W2  = (const float*)d_in[5];
    const float* b2  = (const float*)d_in[6];

    const int N = N_NODES;
    const int E = in_sizes[1];   // 1,600,000 (mod 4 == 0)

    // workspace layout — every region 16-byte aligned (N and E are mult. of 4)
    int* ws_i    = (int*)d_ws;
    int* cnt_src = ws_i;                     // [N]    off 0
    int* cnt_dst = ws_i + N;                 // [N]    off N
    int* rowptr  = ws_i + 2 * N;             // [N+1]  off 2N
    int* bsums   = ws_i + 3 * N + 4;         // [512]  off 3N+4   (16B aligned)
    int* colidx  = ws_i + 3 * N + 516;       // [E]    off 3N+516 (16B aligned)
    float* norms = (float*)(ws_i + 3 * N + 516 + E);  // [2N], 16B aligned
    float* yv    = norms + 2 * N;            // [32N], 16B aligned (float4-read!)

    hipMemsetAsync(ws_i, 0, (size_t)(2 * N) * sizeof(int), stream);

    hist_kernel<<<2048, 256, 0, stream>>>(src, dst, cnt_src, cnt_dst, E);
    norm_kernel<<<(2 * N + 255) / 256, 256, 0, stream>>>(ws_i, norms, 2 * N);

    int nb = (N + 255) / 256;                // 391 <= 512
    scan1_kernel<<<nb, 256, 0, stream>>>(cnt_dst, rowptr, bsums, N);
    scan2_kernel<<<1, 512, 0, stream>>>(bsums, nb);
    scan3_kernel<<<nb, 256, 0, stream>>>(rowptr, cnt_src /*cursor*/, bsums, N, E);
    fill_kernel<<<(E + 255) / 256, 256, 0, stream>>>(src, dst, cnt_src, colidx, E);

    layer1_fused<<<2048, 256, 0, stream>>>((const float4*)x, colidx, rowptr,
                                           norms, norms + N, W1, b1, W2, yv, N);
    agg2_kernel<<<2048, 256, 0, stream>>>((const float4*)yv, colidx, rowptr,
                                          norms + N, b2, (float4*)d_out, N);
}

// Round 5
// 296.717 us; speedup vs baseline: 2.0477x; 1.3010x over previous
//
#include <hip/hip_runtime.h>

#define N_NODES 100000
#define D_IN 32
#define D_HID 64
#define D_OUT 32
#define NBUCK 391      // ceil(N_NODES/256)
#define CHUNK 8192     // edges per partition block
#define CAP   8192     // localfill LDS image capacity (ints)

// ---------------- degree histograms (int) ----------------
__global__ void hist_kernel(const int* __restrict__ src, const int* __restrict__ dst,
                            int* __restrict__ cnt_src, int* __restrict__ cnt_dst, int E) {
    int stride = gridDim.x * blockDim.x;
    for (int e = blockIdx.x * blockDim.x + threadIdx.x; e < E; e += stride) {
        atomicAdd(&cnt_src[src[e]], 1);
        atomicAdd(&cnt_dst[dst[e]], 1);
    }
}

// norms[i] = rsqrt(max(cnt[i],1)); cnt is the contiguous [cnt_src|cnt_dst] block
__global__ void norm_kernel(const int* __restrict__ cnt, float* __restrict__ norms, int n2) {
    int i = blockIdx.x * blockDim.x + threadIdx.x;
    if (i < n2) {
        int d = cnt[i];
        norms[i] = rsqrtf((float)(d < 1 ? 1 : d));
    }
}

// ---------------- 3-kernel exclusive scan of cnt_dst -> rowptr ----------------
__global__ void scan1_kernel(const int* __restrict__ cnt, int* __restrict__ excl,
                             int* __restrict__ bsums, int n) {
    __shared__ int s[256];
    int tid = threadIdx.x;
    int i = blockIdx.x * 256 + tid;
    int v = (i < n) ? cnt[i] : 0;
    s[tid] = v;
    __syncthreads();
    for (int off = 1; off < 256; off <<= 1) {
        int tv = (tid >= off) ? s[tid - off] : 0;
        __syncthreads();
        s[tid] += tv;
        __syncthreads();
    }
    if (i < n) excl[i] = s[tid] - v;
    if (tid == 255) bsums[blockIdx.x] = s[255];
}

__global__ void scan2_kernel(int* __restrict__ bsums, int nb) {
    __shared__ int s[512];
    int tid = threadIdx.x;
    int v = (tid < nb) ? bsums[tid] : 0;
    s[tid] = v;
    __syncthreads();
    for (int off = 1; off < 512; off <<= 1) {
        int tv = (tid >= off) ? s[tid - off] : 0;
        __syncthreads();
        s[tid] += tv;
        __syncthreads();
    }
    if (tid < nb) bsums[tid] = s[tid] - v;
}

__global__ void scan3_kernel(int* __restrict__ rowptr, int* __restrict__ cursor,
                             const int* __restrict__ bsums, int n, int E) {
    int i = blockIdx.x * 256 + threadIdx.x;
    if (i < n) {
        int v = rowptr[i] + bsums[blockIdx.x];
        rowptr[i] = v;
        cursor[i] = v;
    }
    if (i == 0) rowptr[n] = E;
}

// ---------------- bucket cursors: bcur[b] = rowptr[b*256] ----------------
__global__ void bcur_init_kernel(const int* __restrict__ rowptr, int* __restrict__ bcur) {
    int b = threadIdx.x + blockIdx.x * blockDim.x;
    if (b < NBUCK) bcur[b] = rowptr[b << 8];
}

// ---------------- LDS multisplit: scatter edges into bucket-grouped ebuf ----------------
// packed edge: (src<<8) | (dst&255); bucket = dst>>8
__global__ __launch_bounds__(512) void partition_kernel(
    const int* __restrict__ src, const int* __restrict__ dst,
    int* __restrict__ bcur, int* __restrict__ ebuf, int E) {
    __shared__ int lhist[NBUCK];
    __shared__ int sarr[512];
    __shared__ int loff[NBUCK];
    __shared__ int lgb[NBUCK];
    __shared__ int lcur[NBUCK];
    __shared__ int buf[CHUNK];
    int tid = threadIdx.x;
    int base = blockIdx.x * CHUNK;
    int lim = E - base; if (lim > CHUNK) lim = CHUNK;

    for (int i = tid; i < NBUCK; i += 512) lhist[i] = 0;
    __syncthreads();
    for (int k = tid; k < lim; k += 512) {
        int b = dst[base + k] >> 8;
        atomicAdd(&lhist[b], 1);
    }
    __syncthreads();
    // exclusive scan of lhist over 512 slots (NBUCK <= 512)
    int v = (tid < NBUCK) ? lhist[tid] : 0;
    sarr[tid] = v;
    __syncthreads();
    for (int off = 1; off < 512; off <<= 1) {
        int tv = (tid >= off) ? sarr[tid - off] : 0;
        __syncthreads();
        sarr[tid] += tv;
        __syncthreads();
    }
    if (tid < NBUCK) {
        int excl = sarr[tid] - v;
        loff[tid] = excl;
        lcur[tid] = excl;
        lgb[tid]  = v ? atomicAdd(&bcur[tid], v) : 0;
    }
    __syncthreads();
    // stage packed edges bucket-ordered in LDS
    for (int k = tid; k < lim; k += 512) {
        int d = dst[base + k];
        int s = src[base + k];
        int b = d >> 8;
        int p = atomicAdd(&lcur[b], 1);
        buf[p] = (s << 8) | (d & 255);
    }
    __syncthreads();
    // write contiguous runs per bucket
    int w = tid >> 6, lane = tid & 63;
    for (int b = w; b < NBUCK; b += 8) {
        int st = loff[b], len = lhist[b], gb = lgb[b];
        for (int i = lane; i < len; i += 64) ebuf[gb + i] = buf[st + i];
    }
}

// ---------------- per-bucket local fill: ebuf slice -> colidx (coalesced) ----------------
__global__ __launch_bounds__(256) void localfill_kernel(
    const int* __restrict__ ebuf, const int* __restrict__ rowptr,
    int* __restrict__ cursor, int* __restrict__ colidx, int n_nodes) {
    __shared__ int limg[CAP];
    __shared__ int lcur[256];
    int b = blockIdx.x, tid = threadIdx.x;
    int base_node = b << 8;
    int nn = n_nodes - base_node; if (nn > 256) nn = 256;
    int cbase = rowptr[base_node];
    int cend  = rowptr[base_node + nn];
    int len = cend - cbase;
    if (len <= CAP) {
        if (tid < nn) lcur[tid] = rowptr[base_node + tid] - cbase;
        __syncthreads();
        for (int k = tid; k < len; k += 256) {
            int v = ebuf[cbase + k];
            int p = atomicAdd(&lcur[v & 255], 1);
            limg[p] = v >> 8;
        }
        __syncthreads();
        for (int k = tid; k < len; k += 256) colidx[cbase + k] = limg[k];
    } else {
        // slow path (practically never): global scatter via per-node cursor
        for (int k = tid; k < len; k += 256) {
            int v = ebuf[cbase + k];
            int p = atomicAdd(&cursor[base_node + (v & 255)], 1);
            colidx[p] = v >> 8;
        }
    }
}

// ---------------- layer 1 fused: float4 gather-agg + GEMM1 + GEMM2 -> y ----------------
__global__ __launch_bounds__(256) void layer1_fused(
    const float4* __restrict__ x4, const int* __restrict__ colidx,
    const int* __restrict__ rowptr, const float* __restrict__ norm_src,
    const float* __restrict__ norm_dst,
    const float* __restrict__ W1, const float* __restrict__ b1,
    const float* __restrict__ W2, float* __restrict__ y, int n_nodes) {
    __shared__ float W1s[D_IN * D_HID];    // 8 KB
    __shared__ float W2s[D_HID * D_OUT];   // 8 KB
    __shared__ float b1s[D_HID];
    __shared__ float accs[4][D_IN];
    __shared__ float z1s[4][D_HID];
    int t = threadIdx.x;
    for (int i = t; i < D_IN * D_HID; i += 256) W1s[i] = W1[i];
    for (int i = t; i < D_HID * D_OUT; i += 256) W2s[i] = W2[i];
    if (t < D_HID) b1s[t] = b1[t];
    __syncthreads();

    int w = t >> 6, lane = t & 63;
    int eh = lane >> 3;          // edge slot
    int q  = lane & 7;           // feature quad
    int j  = lane & 31;          // GEMM2 output feature
    int kb = (lane >> 5) * 32;   // GEMM2 k-half base

    for (int n = blockIdx.x * 4 + w; n < n_nodes; n += gridDim.x * 4) {
        int start = rowptr[n], end = rowptr[n + 1];
        int deg = end - start;
        float ax = 0.f, ay = 0.f, az = 0.f, aw = 0.f;
        for (int base = 0; base < deg; base += 64) {
            int rem = deg - base;
            int lim = rem < 64 ? rem : 64;
            int lim_up = (lim + 7) & ~7;   // wave-uniform trip count
            int c_reg = (lane < lim) ? colidx[start + base + lane] : 0;
            for (int i = eh; i < lim_up; i += 8) {
                int c = __shfl(c_reg, i);  // all 64 lanes active here
                if (i < lim) {
                    float ns = norm_src[c];
                    float4 v = x4[(long)c * 8 + q];
                    ax = fmaf(v.x, ns, ax); ay = fmaf(v.y, ns, ay);
                    az = fmaf(v.z, ns, az); aw = fmaf(v.w, ns, aw);
                }
            }
        }
        ax += __shfl_xor(ax, 8);  ay += __shfl_xor(ay, 8);  az += __shfl_xor(az, 8);  aw += __shfl_xor(aw, 8);
        ax += __shfl_xor(ax, 16); ay += __shfl_xor(ay, 16); az += __shfl_xor(az, 16); aw += __shfl_xor(aw, 16);
        ax += __shfl_xor(ax, 32); ay += __shfl_xor(ay, 32); az += __shfl_xor(az, 32); aw += __shfl_xor(aw, 32);
        if (lane < 8) {
            accs[w][q * 4 + 0] = ax; accs[w][q * 4 + 1] = ay;
            accs[w][q * 4 + 2] = az; accs[w][q * 4 + 3] = aw;
        }
        float nd = norm_dst[n];
        float s1 = 0.f;
#pragma unroll
        for (int k = 0; k < D_IN; ++k) s1 = fmaf(accs[w][k], W1s[k * D_HID + lane], s1);
        z1s[w][lane] = nd * s1 + b1s[lane];
        float s2 = 0.f;
#pragma unroll
        for (int kk = 0; kk < 32; ++kk) s2 = fmaf(z1s[w][kb + kk], W2s[(kb + kk) * D_OUT + j], s2);
        s2 += __shfl_xor(s2, 32);
        if (lane < 32) y[(long)n * D_OUT + j] = norm_src[n] * s2;
    }
}

// ---------------- layer 2: float4 gather-agg + scale + bias -> out ----------------
__global__ __launch_bounds__(256) void agg2_kernel(
    const float4* __restrict__ y4, const int* __restrict__ colidx,
    const int* __restrict__ rowptr, const float* __restrict__ norm_dst,
    const float* __restrict__ b2, float4* __restrict__ out4, int n_nodes) {
    int t = threadIdx.x;
    int w = t >> 6, lane = t & 63;
    int eh = lane >> 3, q = lane & 7;
    for (int n = blockIdx.x * 4 + w; n < n_nodes; n += gridDim.x * 4) {
        int start = rowptr[n], end = rowptr[n + 1];
        int deg = end - start;
        float ax = 0.f, ay = 0.f, az = 0.f, aw = 0.f;
        for (int base = 0; base < deg; base += 64) {
            int rem = deg - base;
            int lim = rem < 64 ? rem : 64;
            int lim_up = (lim + 7) & ~7;
            int c_reg = (lane < lim) ? colidx[start + base + lane] : 0;
            for (int i = eh; i < lim_up; i += 8) {
                int c = __shfl(c_reg, i);
                if (i < lim) {
                    float4 v = y4[(long)c * 8 + q];
                    ax += v.x; ay += v.y; az += v.z; aw += v.w;
                }
            }
        }
        ax += __shfl_xor(ax, 8);  ay += __shfl_xor(ay, 8);  az += __shfl_xor(az, 8);  aw += __shfl_xor(aw, 8);
        ax += __shfl_xor(ax, 16); ay += __shfl_xor(ay, 16); az += __shfl_xor(az, 16); aw += __shfl_xor(aw, 16);
        ax += __shfl_xor(ax, 32); ay += __shfl_xor(ay, 32); az += __shfl_xor(az, 32); aw += __shfl_xor(aw, 32);
        if (lane < 8) {
            float nd = norm_dst[n];
            const float4 bb = ((const float4*)b2)[q];
            float4 o;
            o.x = fmaf(ax, nd, bb.x); o.y = fmaf(ay, nd, bb.y);
            o.z = fmaf(az, nd, bb.z); o.w = fmaf(aw, nd, bb.w);
            out4[(long)n * 8 + q] = o;
        }
    }
}

extern "C" void kernel_launch(void* const* d_in, const int* in_sizes, int n_in,
                              void* d_out, int out_size, void* d_ws, size_t ws_size,
                              hipStream_t stream) {
    const float* x   = (const float*)d_in[0];
    const int*   src = (const int*)d_in[1];
    const int*   dst = (const int*)d_in[2];
    const float* W1  = (const float*)d_in[3];
    const float* b1  = (const float*)d_in[4];
    const float* W2  = (const float*)d_in[5];
    const float* b2  = (const float*)d_in[6];

    const int N = N_NODES;
    const int E = in_sizes[1];   // 1,600,000

    // workspace layout — every region 16-byte aligned (N, E multiples of 4)
    int* ws_i    = (int*)d_ws;
    int* cnt_src = ws_i;                       // [N]    off 0      (reused as cursor)
    int* cnt_dst = ws_i + N;                   // [N]    off N
    int* rowptr  = ws_i + 2 * N;               // [N+1]  off 2N
    int* bsums   = ws_i + 3 * N + 4;           // [512]  off 3N+4
    int* bcur    = ws_i + 3 * N + 516;         // [512]  off 3N+516
    int* colidx  = ws_i + 3 * N + 1028;        // [E]    off 3N+1028
    float* norms = (float*)(ws_i + 3 * N + 1028 + E);  // [2N]
    float* yv    = norms + 2 * N;              // [32N] floats
    int* ebuf    = (int*)yv;                   // [E] ints — overlays yv (dead then)

    hipMemsetAsync(ws_i, 0, (size_t)(2 * N) * sizeof(int), stream);

    hist_kernel<<<2048, 256, 0, stream>>>(src, dst, cnt_src, cnt_dst, E);
    norm_kernel<<<(2 * N + 255) / 256, 256, 0, stream>>>(ws_i, norms, 2 * N);

    int nb = (N + 255) / 256;                  // 391 <= 512
    scan1_kernel<<<nb, 256, 0, stream>>>(cnt_dst, rowptr, bsums, N);
    scan2_kernel<<<1, 512, 0, stream>>>(bsums, nb);
    scan3_kernel<<<nb, 256, 0, stream>>>(rowptr, cnt_src /*cursor*/, bsums, N, E);

    bcur_init_kernel<<<2, 256, 0, stream>>>(rowptr, bcur);
    int pb = (E + CHUNK - 1) / CHUNK;          // 196 blocks
    partition_kernel<<<pb, 512, 0, stream>>>(src, dst, bcur, ebuf, E);
    localfill_kernel<<<NBUCK, 256, 0, stream>>>(ebuf, rowptr, cnt_src /*cursor*/, colidx, N);

    layer1_fused<<<2048, 256, 0, stream>>>((const float4*)x, colidx, rowptr,
                                           norms, norms + N, W1, b1, W2, yv, N);
    agg2_kernel<<<2048, 256, 0, stream>>>((const float4*)yv, colidx, rowptr,
                                          norms + N, b2, (float4*)d_out, N);
}

// Round 6
// 210.349 us; speedup vs baseline: 2.8885x; 1.4106x over previous
//
#include <hip/hip_runtime.h>

#define N_NODES 100000
#define D_IN 32
#define D_HID 64
#define D_OUT 32
#define NBUCK 391      // ceil(N_NODES/256)
#define CHUNK 8192     // edges per partition block
#define CAP   8192     // localfill LDS image capacity (ints)

// ---------------- bucket-level histograms (LDS-staged, few global atomics) ----------------
__global__ __launch_bounds__(256) void bucket_hist_kernel(
    const int* __restrict__ src, const int* __restrict__ dst,
    int* __restrict__ sb_cnt, int* __restrict__ db_cnt, int E) {
    __shared__ int hs[NBUCK], hd[NBUCK];
    int tid = threadIdx.x;
    for (int i = tid; i < NBUCK; i += 256) { hs[i] = 0; hd[i] = 0; }
    __syncthreads();
    int stride = gridDim.x * 256;
    for (int e = blockIdx.x * 256 + tid; e < E; e += stride) {
        atomicAdd(&hs[src[e] >> 8], 1);
        atomicAdd(&hd[dst[e] >> 8], 1);
    }
    __syncthreads();
    for (int i = tid; i < NBUCK; i += 256) {
        if (hs[i]) atomicAdd(&sb_cnt[i], hs[i]);
        if (hd[i]) atomicAdd(&db_cnt[i], hd[i]);
    }
}

// ---------------- single-block scan of both bucket counters -> bases + cursors ----------------
__global__ __launch_bounds__(512) void bucket_scan_kernel(
    const int* __restrict__ sb_cnt, const int* __restrict__ db_cnt,
    int* __restrict__ sb_base, int* __restrict__ db_base,
    int* __restrict__ sb_cur, int* __restrict__ db_cur, int E) {
    __shared__ int s[512];
    int tid = threadIdx.x;
    int v = (tid < NBUCK) ? sb_cnt[tid] : 0;
    s[tid] = v;
    __syncthreads();
    for (int off = 1; off < 512; off <<= 1) {
        int tv = (tid >= off) ? s[tid - off] : 0;
        __syncthreads(); s[tid] += tv; __syncthreads();
    }
    if (tid < NBUCK) { int e0 = s[tid] - v; sb_base[tid] = e0; sb_cur[tid] = e0; }
    if (tid == 0) sb_base[NBUCK] = E;
    __syncthreads();
    int v2 = (tid < NBUCK) ? db_cnt[tid] : 0;
    s[tid] = v2;
    __syncthreads();
    for (int off = 1; off < 512; off <<= 1) {
        int tv = (tid >= off) ? s[tid - off] : 0;
        __syncthreads(); s[tid] += tv; __syncthreads();
    }
    if (tid < NBUCK) { int e0 = s[tid] - v2; db_base[tid] = e0; db_cur[tid] = e0; }
    if (tid == 0) db_base[NBUCK] = E;
}

// ---------------- LDS multisplit by dst: packed (src<<8)|(dst&255) -> ebuf ----------------
__global__ __launch_bounds__(512) void partition_dst_kernel(
    const int* __restrict__ src, const int* __restrict__ dst,
    int* __restrict__ db_cur, int* __restrict__ ebuf, int E) {
    __shared__ int lhist[NBUCK];
    __shared__ int sarr[512];
    __shared__ int loff[NBUCK];
    __shared__ int lgb[NBUCK];
    __shared__ int lcur[NBUCK];
    __shared__ int buf[CHUNK];
    int tid = threadIdx.x;
    int base = blockIdx.x * CHUNK;
    int lim = E - base; if (lim > CHUNK) lim = CHUNK;

    for (int i = tid; i < NBUCK; i += 512) lhist[i] = 0;
    __syncthreads();
    for (int k = tid; k < lim; k += 512) atomicAdd(&lhist[dst[base + k] >> 8], 1);
    __syncthreads();
    int v = (tid < NBUCK) ? lhist[tid] : 0;
    sarr[tid] = v;
    __syncthreads();
    for (int off = 1; off < 512; off <<= 1) {
        int tv = (tid >= off) ? sarr[tid - off] : 0;
        __syncthreads(); sarr[tid] += tv; __syncthreads();
    }
    if (tid < NBUCK) {
        int excl = sarr[tid] - v;
        loff[tid] = excl; lcur[tid] = excl;
        lgb[tid] = v ? atomicAdd(&db_cur[tid], v) : 0;
    }
    __syncthreads();
    for (int k = tid; k < lim; k += 512) {
        int d = dst[base + k], s0 = src[base + k];
        int p = atomicAdd(&lcur[d >> 8], 1);
        buf[p] = (s0 << 8) | (d & 255);
    }
    __syncthreads();
    int w = tid >> 6, lane = tid & 63;
    for (int b = w; b < NBUCK; b += 8) {
        int st = loff[b], len = lhist[b], gb = lgb[b];
        for (int i = lane; i < len; i += 64) ebuf[gb + i] = buf[st + i];
    }
}

// ---------------- LDS multisplit by src, low byte only -> sbuf (bytes) ----------------
__global__ __launch_bounds__(512) void partition_src_kernel(
    const int* __restrict__ src, int* __restrict__ sb_cur,
    unsigned char* __restrict__ sbuf, int E) {
    __shared__ int lhist[NBUCK];
    __shared__ int sarr[512];
    __shared__ int loff[NBUCK];
    __shared__ int lgb[NBUCK];
    __shared__ int lcur[NBUCK];
    __shared__ unsigned char buf[CHUNK];
    int tid = threadIdx.x;
    int base = blockIdx.x * CHUNK;
    int lim = E - base; if (lim > CHUNK) lim = CHUNK;

    for (int i = tid; i < NBUCK; i += 512) lhist[i] = 0;
    __syncthreads();
    for (int k = tid; k < lim; k += 512) atomicAdd(&lhist[src[base + k] >> 8], 1);
    __syncthreads();
    int v = (tid < NBUCK) ? lhist[tid] : 0;
    sarr[tid] = v;
    __syncthreads();
    for (int off = 1; off < 512; off <<= 1) {
        int tv = (tid >= off) ? sarr[tid - off] : 0;
        __syncthreads(); sarr[tid] += tv; __syncthreads();
    }
    if (tid < NBUCK) {
        int excl = sarr[tid] - v;
        loff[tid] = excl; lcur[tid] = excl;
        lgb[tid] = v ? atomicAdd(&sb_cur[tid], v) : 0;
    }
    __syncthreads();
    for (int k = tid; k < lim; k += 512) {
        int s0 = src[base + k];
        int p = atomicAdd(&lcur[s0 >> 8], 1);
        buf[p] = (unsigned char)(s0 & 255);
    }
    __syncthreads();
    int w = tid >> 6, lane = tid & 63;
    for (int b = w; b < NBUCK; b += 8) {
        int st = loff[b], len = lhist[b], gb = lgb[b];
        for (int i = lane; i < len; i += 64) sbuf[gb + i] = buf[st + i];
    }
}

// ---------------- per-bucket src counting -> norm_src (coalesced) ----------------
__global__ __launch_bounds__(256) void src_norm_kernel(
    const unsigned char* __restrict__ sbuf, const int* __restrict__ sb_base,
    float* __restrict__ norm_src, int n_nodes) {
    __shared__ int cnt[256];
    int b = blockIdx.x, tid = threadIdx.x;
    int st = sb_base[b], en = sb_base[b + 1];
    cnt[tid] = 0;
    __syncthreads();
    for (int k = st + tid; k < en; k += 256) atomicAdd(&cnt[sbuf[k]], 1);
    __syncthreads();
    int node = (b << 8) + tid;
    if (node < n_nodes) {
        int d = cnt[tid];
        norm_src[node] = rsqrtf((float)(d < 1 ? 1 : d));
    }
}

// ---------------- per-bucket: count + scan -> rowptr & norm_dst, then fill colidx ----------------
__global__ __launch_bounds__(256) void localfill_kernel(
    const int* __restrict__ ebuf, const int* __restrict__ db_base,
    int* __restrict__ rowptr, float* __restrict__ norm_dst,
    int* __restrict__ colidx, int n_nodes, int E) {
    __shared__ int limg[CAP];
    __shared__ int cnt[256];
    __shared__ int sc[256];
    int b = blockIdx.x, tid = threadIdx.x;
    int base_node = b << 8;
    int nn = n_nodes - base_node; if (nn > 256) nn = 256;
    int cbase = db_base[b], cend = db_base[b + 1];
    int len = cend - cbase;
    cnt[tid] = 0;
    __syncthreads();
    for (int k = tid; k < len; k += 256) atomicAdd(&cnt[ebuf[cbase + k] & 255], 1);
    __syncthreads();
    int v = cnt[tid];
    sc[tid] = v;
    __syncthreads();
    for (int off = 1; off < 256; off <<= 1) {
        int tv = (tid >= off) ? sc[tid - off] : 0;
        __syncthreads(); sc[tid] += tv; __syncthreads();
    }
    int excl = sc[tid] - v;
    if (tid < nn) {
        rowptr[base_node + tid] = cbase + excl;
        norm_dst[base_node + tid] = rsqrtf((float)(v < 1 ? 1 : v));
    }
    if (b == NBUCK - 1 && tid == 0) rowptr[n_nodes] = E;
    __syncthreads();
    cnt[tid] = excl;   // reuse as local cursor
    __syncthreads();
    if (len <= CAP) {
        for (int k = tid; k < len; k += 256) {
            int v2 = ebuf[cbase + k];
            int p = atomicAdd(&cnt[v2 & 255], 1);
            limg[p] = v2 >> 8;
        }
        __syncthreads();
        for (int k = tid; k < len; k += 256) colidx[cbase + k] = limg[k];
    } else {
        // slow path (practically never): scatter straight to global
        for (int k = tid; k < len; k += 256) {
            int v2 = ebuf[cbase + k];
            int p = atomicAdd(&cnt[v2 & 255], 1);
            colidx[cbase + p] = v2 >> 8;
        }
    }
}

// ---------------- layer 1 fused: float4 gather-agg + GEMM1 + GEMM2 -> y ----------------
__global__ __launch_bounds__(256) void layer1_fused(
    const float4* __restrict__ x4, const int* __restrict__ colidx,
    const int* __restrict__ rowptr, const float* __restrict__ norm_src,
    const float* __restrict__ norm_dst,
    const float* __restrict__ W1, const float* __restrict__ b1,
    const float* __restrict__ W2, float* __restrict__ y, int n_nodes) {
    __shared__ float W1s[D_IN * D_HID];
    __shared__ float W2s[D_HID * D_OUT];
    __shared__ float b1s[D_HID];
    __shared__ float accs[4][D_IN];
    __shared__ float z1s[4][D_HID];
    int t = threadIdx.x;
    for (int i = t; i < D_IN * D_HID; i += 256) W1s[i] = W1[i];
    for (int i = t; i < D_HID * D_OUT; i += 256) W2s[i] = W2[i];
    if (t < D_HID) b1s[t] = b1[t];
    __syncthreads();

    int w = t >> 6, lane = t & 63;
    int eh = lane >> 3;          // edge slot
    int q  = lane & 7;           // feature quad
    int j  = lane & 31;          // GEMM2 output feature
    int kb = (lane >> 5) * 32;   // GEMM2 k-half base

    for (int n = blockIdx.x * 4 + w; n < n_nodes; n += gridDim.x * 4) {
        int start = rowptr[n], end = rowptr[n + 1];
        int deg = end - start;
        float ax = 0.f, ay = 0.f, az = 0.f, aw = 0.f;
        for (int base = 0; base < deg; base += 64) {
            int rem = deg - base;
            int lim = rem < 64 ? rem : 64;
            int lim_up = (lim + 7) & ~7;
            int c_reg = (lane < lim) ? colidx[start + base + lane] : 0;
            for (int i = eh; i < lim_up; i += 8) {
                int c = __shfl(c_reg, i);
                if (i < lim) {
                    float ns = norm_src[c];
                    float4 v = x4[(long)c * 8 + q];
                    ax = fmaf(v.x, ns, ax); ay = fmaf(v.y, ns, ay);
                    az = fmaf(v.z, ns, az); aw = fmaf(v.w, ns, aw);
                }
            }
        }
        ax += __shfl_xor(ax, 8);  ay += __shfl_xor(ay, 8);  az += __shfl_xor(az, 8);  aw += __shfl_xor(aw, 8);
        ax += __shfl_xor(ax, 16); ay += __shfl_xor(ay, 16); az += __shfl_xor(az, 16); aw += __shfl_xor(aw, 16);
        ax += __shfl_xor(ax, 32); ay += __shfl_xor(ay, 32); az += __shfl_xor(az, 32); aw += __shfl_xor(aw, 32);
        if (lane < 8) {
            accs[w][q * 4 + 0] = ax; accs[w][q * 4 + 1] = ay;
            accs[w][q * 4 + 2] = az; accs[w][q * 4 + 3] = aw;
        }
        float nd = norm_dst[n];
        float s1 = 0.f;
#pragma unroll
        for (int k = 0; k < D_IN; ++k) s1 = fmaf(accs[w][k], W1s[k * D_HID + lane], s1);
        z1s[w][lane] = nd * s1 + b1s[lane];
        float s2 = 0.f;
#pragma unroll
        for (int kk = 0; kk < 32; ++kk) s2 = fmaf(z1s[w][kb + kk], W2s[(kb + kk) * D_OUT + j], s2);
        s2 += __shfl_xor(s2, 32);
        if (lane < 32) y[(long)n * D_OUT + j] = norm_src[n] * s2;
    }
}

// ---------------- layer 2: float4 gather-agg + scale + bias -> out ----------------
__global__ __launch_bounds__(256) void agg2_kernel(
    const float4* __restrict__ y4, const int* __restrict__ colidx,
    const int* __restrict__ rowptr, const float* __restrict__ norm_dst,
    const float* __restrict__ b2, float4* __restrict__ out4, int n_nodes) {
    int t = threadIdx.x;
    int w = t >> 6, lane = t & 63;
    int eh = lane >> 3, q = lane & 7;
    for (int n = blockIdx.x * 4 + w; n < n_nodes; n += gridDim.x * 4) {
        int start = rowptr[n], end = rowptr[n + 1];
        int deg = end - start;
        float ax = 0.f, ay = 0.f, az = 0.f, aw = 0.f;
        for (int base = 0; base < deg; base += 64) {
            int rem = deg - base;
            int lim = rem < 64 ? rem : 64;
            int lim_up = (lim + 7) & ~7;
            int c_reg = (lane < lim) ? colidx[start + base + lane] : 0;
            for (int i = eh; i < lim_up; i += 8) {
                int c = __shfl(c_reg, i);
                if (i < lim) {
                    float4 v = y4[(long)c * 8 + q];
                    ax += v.x; ay += v.y; az += v.z; aw += v.w;
                }
            }
        }
        ax += __shfl_xor(ax, 8);  ay += __shfl_xor(ay, 8);  az += __shfl_xor(az, 8);  aw += __shfl_xor(aw, 8);
        ax += __shfl_xor(ax, 16); ay += __shfl_xor(ay, 16); az += __shfl_xor(az, 16); aw += __shfl_xor(aw, 16);
        ax += __shfl_xor(ax, 32); ay += __shfl_xor(ay, 32); az += __shfl_xor(az, 32); aw += __shfl_xor(aw, 32);
        if (lane < 8) {
            float nd = norm_dst[n];
            const float4 bb = ((const float4*)b2)[q];
            float4 o;
            o.x = fmaf(ax, nd, bb.x); o.y = fmaf(ay, nd, bb.y);
            o.z = fmaf(az, nd, bb.z); o.w = fmaf(aw, nd, bb.w);
            out4[(long)n * 8 + q] = o;
        }
    }
}

extern "C" void kernel_launch(void* const* d_in, const int* in_sizes, int n_in,
                              void* d_out, int out_size, void* d_ws, size_t ws_size,
                              hipStream_t stream) {
    const float* x   = (const float*)d_in[0];
    const int*   src = (const int*)d_in[1];
    const int*   dst = (const int*)d_in[2];
    const float* W1  = (const float*)d_in[3];
    const float* b1  = (const float*)d_in[4];
    const float* W2  = (const float*)d_in[5];
    const float* b2  = (const float*)d_in[6];

    const int N = N_NODES;
    const int E = in_sizes[1];   // 1,600,000

    // workspace layout (ints; every region 16-byte aligned)
    int* ws_i    = (int*)d_ws;
    int* sb_cnt  = ws_i;                   // [512]
    int* db_cnt  = ws_i + 512;             // [512]
    int* sb_base = ws_i + 1024;            // [512] (NBUCK+1 used)
    int* db_base = ws_i + 1536;            // [512]
    int* sb_cur  = ws_i + 2048;            // [512]
    int* db_cur  = ws_i + 2560;            // [512]
    int* rowptr  = ws_i + 3072;            // [N+4]
    int* colidx  = ws_i + 3072 + N + 4;    // [E]
    float* norms = (float*)(colidx + E);   // [2N]: norm_src | norm_dst
    float* yv    = norms + 2 * N;          // [32N] floats
    int* ebuf    = (int*)yv;               // [E] ints   (overlays yv, dead by then)
    unsigned char* sbuf = (unsigned char*)(ebuf + E);  // [E] bytes (also in yv region)

    // zero the bucket counters only (4 KB)
    hipMemsetAsync(ws_i, 0, 1024 * sizeof(int), stream);

    bucket_hist_kernel<<<256, 256, 0, stream>>>(src, dst, sb_cnt, db_cnt, E);
    bucket_scan_kernel<<<1, 512, 0, stream>>>(sb_cnt, db_cnt, sb_base, db_base,
                                              sb_cur, db_cur, E);

    int pb = (E + CHUNK - 1) / CHUNK;      // 196 blocks
    partition_dst_kernel<<<pb, 512, 0, stream>>>(src, dst, db_cur, ebuf, E);
    partition_src_kernel<<<pb, 512, 0, stream>>>(src, sb_cur, sbuf, E);
    src_norm_kernel<<<NBUCK, 256, 0, stream>>>(sbuf, sb_base, norms, N);
    localfill_kernel<<<NBUCK, 256, 0, stream>>>(ebuf, db_base, rowptr, norms + N,
                                                colidx, N, E);

    layer1_fused<<<2048, 256, 0, stream>>>((const float4*)x, colidx, rowptr,
                                           norms, norms + N, W1, b1, W2, yv, N);
    agg2_kernel<<<2048, 256, 0, stream>>>((const float4*)yv, colidx, rowptr,
                                          norms + N, b2, (float4*)d_out, N);
}

// Round 7
// 194.728 us; speedup vs baseline: 3.1202x; 1.0802x over previous
//
#include <hip/hip_runtime.h>

#define N_NODES 100000
#define D_IN 32
#define D_HID 64
#define D_OUT 32
#define NBUCK 391      // ceil(N_NODES/256)
#define CHUNK 8192     // edges per partition block
#define CAP   8192     // localfill LDS image capacity (ints)

#define RED3(a) { a += __shfl_xor(a, 8); a += __shfl_xor(a, 16); a += __shfl_xor(a, 32); }

// ---------------- bucket-level histograms (LDS-staged) ----------------
__global__ __launch_bounds__(256) void bucket_hist_kernel(
    const int* __restrict__ src, const int* __restrict__ dst,
    int* __restrict__ sb_cnt, int* __restrict__ db_cnt, int E) {
    __shared__ int hs[NBUCK], hd[NBUCK];
    int tid = threadIdx.x;
    for (int i = tid; i < NBUCK; i += 256) { hs[i] = 0; hd[i] = 0; }
    __syncthreads();
    int stride = gridDim.x * 256;
    for (int e = blockIdx.x * 256 + tid; e < E; e += stride) {
        atomicAdd(&hs[src[e] >> 8], 1);
        atomicAdd(&hd[dst[e] >> 8], 1);
    }
    __syncthreads();
    for (int i = tid; i < NBUCK; i += 256) {
        if (hs[i]) atomicAdd(&sb_cnt[i], hs[i]);
        if (hd[i]) atomicAdd(&db_cnt[i], hd[i]);
    }
}

// ---------------- single-block scan of both bucket counters ----------------
__global__ __launch_bounds__(512) void bucket_scan_kernel(
    const int* __restrict__ sb_cnt, const int* __restrict__ db_cnt,
    int* __restrict__ sb_base, int* __restrict__ db_base,
    int* __restrict__ sb_cur, int* __restrict__ db_cur, int E) {
    __shared__ int s[512];
    int tid = threadIdx.x;
    int v = (tid < NBUCK) ? sb_cnt[tid] : 0;
    s[tid] = v;
    __syncthreads();
    for (int off = 1; off < 512; off <<= 1) {
        int tv = (tid >= off) ? s[tid - off] : 0;
        __syncthreads(); s[tid] += tv; __syncthreads();
    }
    if (tid < NBUCK) { int e0 = s[tid] - v; sb_base[tid] = e0; sb_cur[tid] = e0; }
    if (tid == 0) sb_base[NBUCK] = E;
    __syncthreads();
    int v2 = (tid < NBUCK) ? db_cnt[tid] : 0;
    s[tid] = v2;
    __syncthreads();
    for (int off = 1; off < 512; off <<= 1) {
        int tv = (tid >= off) ? s[tid - off] : 0;
        __syncthreads(); s[tid] += tv; __syncthreads();
    }
    if (tid < NBUCK) { int e0 = s[tid] - v2; db_base[tid] = e0; db_cur[tid] = e0; }
    if (tid == 0) db_base[NBUCK] = E;
}

// ---------------- merged LDS multisplit: dst->ebuf (packed), src->sbuf (bytes) ----------------
__global__ __launch_bounds__(512) void partition_both_kernel(
    const int* __restrict__ src, const int* __restrict__ dst,
    int* __restrict__ sb_cur, int* __restrict__ db_cur,
    int* __restrict__ ebuf, unsigned char* __restrict__ sbuf, int E) {
    __shared__ int dh[NBUCK], sh_[NBUCK];
    __shared__ int sarr[512];
    __shared__ int dloff[NBUCK], dgb[NBUCK], dcur[NBUCK];
    __shared__ int sloff[NBUCK], sgb[NBUCK], scur[NBUCK];
    __shared__ int dbuf[CHUNK];
    __shared__ unsigned char sbytes[CHUNK];
    int tid = threadIdx.x;
    int base = blockIdx.x * CHUNK;
    int lim = E - base; if (lim > CHUNK) lim = CHUNK;

    for (int i = tid; i < NBUCK; i += 512) { dh[i] = 0; sh_[i] = 0; }
    __syncthreads();
    for (int k = tid; k < lim; k += 512) {
        atomicAdd(&dh[dst[base + k] >> 8], 1);
        atomicAdd(&sh_[src[base + k] >> 8], 1);
    }
    __syncthreads();
    // scan dh
    int v = (tid < NBUCK) ? dh[tid] : 0;
    sarr[tid] = v;
    __syncthreads();
    for (int off = 1; off < 512; off <<= 1) {
        int tv = (tid >= off) ? sarr[tid - off] : 0;
        __syncthreads(); sarr[tid] += tv; __syncthreads();
    }
    if (tid < NBUCK) {
        int excl = sarr[tid] - v;
        dloff[tid] = excl; dcur[tid] = excl;
        dgb[tid] = v ? atomicAdd(&db_cur[tid], v) : 0;
    }
    __syncthreads();
    // scan sh_
    int v2 = (tid < NBUCK) ? sh_[tid] : 0;
    sarr[tid] = v2;
    __syncthreads();
    for (int off = 1; off < 512; off <<= 1) {
        int tv = (tid >= off) ? sarr[tid - off] : 0;
        __syncthreads(); sarr[tid] += tv; __syncthreads();
    }
    if (tid < NBUCK) {
        int excl = sarr[tid] - v2;
        sloff[tid] = excl; scur[tid] = excl;
        sgb[tid] = v2 ? atomicAdd(&sb_cur[tid], v2) : 0;
    }
    __syncthreads();
    // stage both in LDS
    for (int k = tid; k < lim; k += 512) {
        int d = dst[base + k], s0 = src[base + k];
        int p = atomicAdd(&dcur[d >> 8], 1);
        dbuf[p] = (s0 << 8) | (d & 255);
        int p2 = atomicAdd(&scur[s0 >> 8], 1);
        sbytes[p2] = (unsigned char)(s0 & 255);
    }
    __syncthreads();
    // write contiguous runs
    int w = tid >> 6, lane = tid & 63;
    for (int b = w; b < NBUCK; b += 8) {
        int st = dloff[b], len = dh[b], gb = dgb[b];
        for (int i = lane; i < len; i += 64) ebuf[gb + i] = dbuf[st + i];
        int st2 = sloff[b], len2 = sh_[b], gb2 = sgb[b];
        for (int i = lane; i < len2; i += 64) sbuf[gb2 + i] = sbytes[st2 + i];
    }
}

// ---------------- per-bucket src count -> norm_src, and xs = x * norm_src ----------------
__global__ __launch_bounds__(256) void src_norm_prescale_kernel(
    const unsigned char* __restrict__ sbuf, const int* __restrict__ sb_base,
    const float4* __restrict__ x4, float4* __restrict__ xs4,
    float* __restrict__ norm_src, int n_nodes) {
    __shared__ int cnt[256];
    __shared__ float nsl[256];
    int b = blockIdx.x, tid = threadIdx.x;
    int st = sb_base[b], en = sb_base[b + 1];
    cnt[tid] = 0;
    __syncthreads();
    for (int k = st + tid; k < en; k += 256) atomicAdd(&cnt[sbuf[k]], 1);
    __syncthreads();
    int base_node = b << 8;
    int nn = n_nodes - base_node; if (nn > 256) nn = 256;
    if (tid < nn) {
        int d = cnt[tid];
        float ns = rsqrtf((float)(d < 1 ? 1 : d));
        norm_src[base_node + tid] = ns;
        nsl[tid] = ns;
    }
    __syncthreads();
    for (int k = tid; k < nn * 8; k += 256) {
        float4 v = x4[((long)base_node << 3) + k];
        float s = nsl[k >> 3];
        v.x *= s; v.y *= s; v.z *= s; v.w *= s;
        xs4[((long)base_node << 3) + k] = v;
    }
}

// ---------------- per-bucket: count + scan -> rowptr & norm_dst, fill colidx ----------------
__global__ __launch_bounds__(256) void localfill_kernel(
    const int* __restrict__ ebuf, const int* __restrict__ db_base,
    int* __restrict__ rowptr, float* __restrict__ norm_dst,
    int* __restrict__ colidx, int n_nodes, int E) {
    __shared__ int limg[CAP];
    __shared__ int cnt[256];
    __shared__ int sc[256];
    int b = blockIdx.x, tid = threadIdx.x;
    int base_node = b << 8;
    int nn = n_nodes - base_node; if (nn > 256) nn = 256;
    int cbase = db_base[b], cend = db_base[b + 1];
    int len = cend - cbase;
    cnt[tid] = 0;
    __syncthreads();
    for (int k = tid; k < len; k += 256) atomicAdd(&cnt[ebuf[cbase + k] & 255], 1);
    __syncthreads();
    int v = cnt[tid];
    sc[tid] = v;
    __syncthreads();
    for (int off = 1; off < 256; off <<= 1) {
        int tv = (tid >= off) ? sc[tid - off] : 0;
        __syncthreads(); sc[tid] += tv; __syncthreads();
    }
    int excl = sc[tid] - v;
    if (tid < nn) {
        rowptr[base_node + tid] = cbase + excl;
        norm_dst[base_node + tid] = rsqrtf((float)(v < 1 ? 1 : v));
    }
    if (b == NBUCK - 1 && tid == 0) rowptr[n_nodes] = E;
    __syncthreads();
    cnt[tid] = excl;   // reuse as local cursor
    __syncthreads();
    if (len <= CAP) {
        for (int k = tid; k < len; k += 256) {
            int v2 = ebuf[cbase + k];
            int p = atomicAdd(&cnt[v2 & 255], 1);
            limg[p] = v2 >> 8;
        }
        __syncthreads();
        for (int k = tid; k < len; k += 256) colidx[cbase + k] = limg[k];
    } else {
        for (int k = tid; k < len; k += 256) {
            int v2 = ebuf[cbase + k];
            int p = atomicAdd(&cnt[v2 & 255], 1);
            colidx[cbase + p] = v2 >> 8;
        }
    }
}

// ---------------- layer 1 fused: 2-node/wave gather + GEMM1 + GEMM2 -> y ----------------
__global__ __launch_bounds__(256) void layer1_fused(
    const float4* __restrict__ xs4, const int* __restrict__ colidx,
    const int* __restrict__ rowptr, const float* __restrict__ norm_src,
    const float* __restrict__ norm_dst,
    const float* __restrict__ W1, const float* __restrict__ b1,
    const float* __restrict__ W2, float* __restrict__ y, int n_nodes) {
    __shared__ float W1s[D_IN * D_HID];
    __shared__ float W2s[D_HID * D_OUT];
    __shared__ float b1s[D_HID];
    __shared__ float accs[4][2][D_IN];
    __shared__ float z1s[4][2][D_HID];
    int t = threadIdx.x;
    for (int i = t; i < D_IN * D_HID; i += 256) { W1s[i] = W1[i]; W2s[i] = W2[i]; }
    if (t < D_HID) b1s[t] = b1[t];
    __syncthreads();

    int w = t >> 6, lane = t & 63;
    int eh = lane >> 3;          // edge slot (0..7)
    int q  = lane & 7;           // feature quad
    int j  = lane & 31;          // GEMM2 output feature
    int half = lane >> 5;        // GEMM2 node select
    int npairs = (n_nodes + 1) >> 1;

    for (int p = blockIdx.x * 4 + w; p < npairs; p += gridDim.x * 4) {
        int nA = p * 2, nB = nA + 1;
        bool hasB = nB < n_nodes;
        int sA = rowptr[nA], eA = rowptr[nA + 1];
        int sB = hasB ? rowptr[nB] : 0, eB = hasB ? rowptr[nB + 1] : 0;
        int dA = eA - sA, dB = eB - sB;
        int dmax = dA > dB ? dA : dB;
        float aAx = 0.f, aAy = 0.f, aAz = 0.f, aAw = 0.f;
        float aBx = 0.f, aBy = 0.f, aBz = 0.f, aBw = 0.f;
        for (int base = 0; base < dmax; base += 64) {
            int limA = dA - base; limA = limA < 0 ? 0 : (limA > 64 ? 64 : limA);
            int limB = dB - base; limB = limB < 0 ? 0 : (limB > 64 ? 64 : limB);
            int cA = (lane < limA) ? colidx[sA + base + lane] : 0;
            int cB = (lane < limB) ? colidx[sB + base + lane] : 0;
            int lm = limA > limB ? limA : limB;
            int lim_up = (lm + 7) & ~7;
            for (int i = eh; i < lim_up; i += 8) {
                int ca = __shfl(cA, i), cb = __shfl(cB, i);
                if (i < limA) {
                    float4 v = xs4[(long)ca * 8 + q];
                    aAx += v.x; aAy += v.y; aAz += v.z; aAw += v.w;
                }
                if (i < limB) {
                    float4 v = xs4[(long)cb * 8 + q];
                    aBx += v.x; aBy += v.y; aBz += v.z; aBw += v.w;
                }
            }
        }
        RED3(aAx) RED3(aAy) RED3(aAz) RED3(aAw)
        RED3(aBx) RED3(aBy) RED3(aBz) RED3(aBw)
        if (lane < 16) {
            int s = lane >> 3, qq = lane & 7;
            accs[w][s][qq * 4 + 0] = s ? aBx : aAx;
            accs[w][s][qq * 4 + 1] = s ? aBy : aAy;
            accs[w][s][qq * 4 + 2] = s ? aBz : aAz;
            accs[w][s][qq * 4 + 3] = s ? aBw : aAw;
        }
        float ndA = norm_dst[nA], ndB = hasB ? norm_dst[nB] : 0.f;
        float s1A = 0.f, s1B = 0.f;
#pragma unroll
        for (int k = 0; k < D_IN; ++k) {
            float wv = W1s[k * D_HID + lane];
            s1A = fmaf(accs[w][0][k], wv, s1A);
            s1B = fmaf(accs[w][1][k], wv, s1B);
        }
        z1s[w][0][lane] = ndA * s1A + b1s[lane];
        z1s[w][1][lane] = ndB * s1B + b1s[lane];
        float s2 = 0.f;
#pragma unroll
        for (int k = 0; k < D_HID; ++k) s2 = fmaf(z1s[w][half][k], W2s[k * D_OUT + j], s2);
        int nn_ = half ? nB : nA;
        if (half == 0 || hasB) y[(long)nn_ * D_OUT + j] = norm_src[nn_] * s2;
    }
}

// ---------------- layer 2: 2-node/wave gather + scale + bias -> out ----------------
__global__ __launch_bounds__(256) void agg2_kernel(
    const float4* __restrict__ y4, const int* __restrict__ colidx,
    const int* __restrict__ rowptr, const float* __restrict__ norm_dst,
    const float* __restrict__ b2, float4* __restrict__ out4, int n_nodes) {
    int t = threadIdx.x;
    int w = t >> 6, lane = t & 63;
    int eh = lane >> 3, q = lane & 7;
    int npairs = (n_nodes + 1) >> 1;
    for (int p = blockIdx.x * 4 + w; p < npairs; p += gridDim.x * 4) {
        int nA = p * 2, nB = nA + 1;
        bool hasB = nB < n_nodes;
        int sA = rowptr[nA], eA = rowptr[nA + 1];
        int sB = hasB ? rowptr[nB] : 0, eB = hasB ? rowptr[nB + 1] : 0;
        int dA = eA - sA, dB = eB - sB;
        int dmax = dA > dB ? dA : dB;
        float aAx = 0.f, aAy = 0.f, aAz = 0.f, aAw = 0.f;
        float aBx = 0.f, aBy = 0.f, aBz = 0.f, aBw = 0.f;
        for (int base = 0; base < dmax; base += 64) {
            int limA = dA - base; limA = limA < 0 ? 0 : (limA > 64 ? 64 : limA);
            int limB = dB - base; limB = limB < 0 ? 0 : (limB > 64 ? 64 : limB);
            int cA = (lane < limA) ? colidx[sA + base + lane] : 0;
            int cB = (lane < limB) ? colidx[sB + base + lane] : 0;
            int lm = limA > limB ? limA : limB;
            int lim_up = (lm + 7) & ~7;
            for (int i = eh; i < lim_up; i += 8) {
                int ca = __shfl(cA, i), cb = __shfl(cB, i);
                if (i < limA) {
                    float4 v = y4[(long)ca * 8 + q];
                    aAx += v.x; aAy += v.y; aAz += v.z; aAw += v.w;
                }
                if (i < limB) {
                    float4 v = y4[(long)cb * 8 + q];
                    aBx += v.x; aBy += v.y; aBz += v.z; aBw += v.w;
                }
            }
        }
        RED3(aAx) RED3(aAy) RED3(aAz) RED3(aAw)
        RED3(aBx) RED3(aBy) RED3(aBz) RED3(aBw)
        if (lane < 16) {
            int s = lane >> 3;
            int nn_ = s ? nB : nA;
            if (!s || hasB) {
                float nd = norm_dst[nn_];
                const float4 bb = ((const float4*)b2)[q];
                float4 o;
                o.x = fmaf(s ? aBx : aAx, nd, bb.x);
                o.y = fmaf(s ? aBy : aAy, nd, bb.y);
                o.z = fmaf(s ? aBz : aAz, nd, bb.z);
                o.w = fmaf(s ? aBw : aAw, nd, bb.w);
                out4[(long)nn_ * 8 + q] = o;
            }
        }
    }
}

extern "C" void kernel_launch(void* const* d_in, const int* in_sizes, int n_in,
                              void* d_out, int out_size, void* d_ws, size_t ws_size,
                              hipStream_t stream) {
    const float* x   = (const float*)d_in[0];
    const int*   src = (const int*)d_in[1];
    const int*   dst = (const int*)d_in[2];
    const float* W1  = (const float*)d_in[3];
    const float* b1  = (const float*)d_in[4];
    const float* W2  = (const float*)d_in[5];
    const float* b2  = (const float*)d_in[6];

    const int N = N_NODES;
    const int E = in_sizes[1];   // 1,600,000

    // workspace layout (ints; every region 16-byte aligned); total ~33.2 MB
    int* ws_i    = (int*)d_ws;
    int* sb_cnt  = ws_i;                   // [512]
    int* db_cnt  = ws_i + 512;             // [512]
    int* sb_base = ws_i + 1024;            // [512]
    int* db_base = ws_i + 1536;            // [512]
    int* sb_cur  = ws_i + 2048;            // [512]
    int* db_cur  = ws_i + 2560;            // [512]
    int* rowptr  = ws_i + 3072;            // [N+4]
    int* colidx  = ws_i + 3072 + N + 4;    // [E]
    float* norms = (float*)(colidx + E);   // [2N]: norm_src | norm_dst
    float* yv    = norms + 2 * N;          // [32N] floats
    float* xs    = yv + 32 * N;            // [32N] floats (pre-scaled x)
    int* ebuf    = (int*)yv;               // [E] ints   (overlays yv; dead before layer1)
    unsigned char* sbuf = (unsigned char*)(ebuf + E);  // [E] bytes (also in yv region)

    hipMemsetAsync(ws_i, 0, 1024 * sizeof(int), stream);

    bucket_hist_kernel<<<256, 256, 0, stream>>>(src, dst, sb_cnt, db_cnt, E);
    bucket_scan_kernel<<<1, 512, 0, stream>>>(sb_cnt, db_cnt, sb_base, db_base,
                                              sb_cur, db_cur, E);

    int pb = (E + CHUNK - 1) / CHUNK;      // 196 blocks
    partition_both_kernel<<<pb, 512, 0, stream>>>(src, dst, sb_cur, db_cur,
                                                  ebuf, sbuf, E);
    src_norm_prescale_kernel<<<NBUCK, 256, 0, stream>>>(sbuf, sb_base,
                                                        (const float4*)x, (float4*)xs,
                                                        norms, N);
    localfill_kernel<<<NBUCK, 256, 0, stream>>>(ebuf, db_base, rowptr, norms + N,
                                                colidx, N, E);

    layer1_fused<<<2048, 256, 0, stream>>>((const float4*)xs, colidx, rowptr,
                                           norms, norms + N, W1, b1, W2, yv, N);
    agg2_kernel<<<2048, 256, 0, stream>>>((const float4*)yv, colidx, rowptr,
                                          norms + N, b2, (float4*)d_out, N);
}